// Round 2
// baseline (682.295 us; speedup 1.0000x reference)
//
#include <hip/hip_runtime.h>
#include <math.h>

#define NG 1000
#define SCAN_T 1024
#define POOL_L 128

// ---- integer in-degree over dst ----
__global__ void deg_kernel(const int* __restrict__ dst, int* __restrict__ degi, int E) {
    int i = blockIdx.x * blockDim.x + threadIdx.x;
    if (i < E) atomicAdd(&degi[dst[i]], 1);
}

// ---- single-block exclusive scan: degi -> rowptr, fill(=degi overwritten), plus dinv ----
__global__ void __launch_bounds__(SCAN_T) scan_kernel(int* __restrict__ degfill,
                                                      float* __restrict__ dinv,
                                                      int* __restrict__ rowptr, int N) {
    __shared__ int sdata[SCAN_T];
    int t = threadIdx.x;
    int chunk = (N + SCAN_T - 1) / SCAN_T;
    int beg = t * chunk, end = beg + chunk;
    if (end > N) end = N;
    int sum = 0;
    for (int i = beg; i < end; i++) {
        int dg = degfill[i];
        dinv[i] = rsqrtf((float)dg + 1.0f);   // self-loop adds +1
        sum += dg;
    }
    sdata[t] = sum;
    __syncthreads();
    for (int off = 1; off < SCAN_T; off <<= 1) {
        int v = 0;
        if (t >= off) v = sdata[t - off];
        __syncthreads();
        if (t >= off) sdata[t] += v;
        __syncthreads();
    }
    int run = sdata[t] - sum;                  // exclusive prefix
    for (int i = beg; i < end; i++) {
        int dg = degfill[i];
        rowptr[i]  = run;
        degfill[i] = run;                      // becomes the fill cursor
        run += dg;
    }
    if (t == SCAN_T - 1) rowptr[N] = run;
}

// ---- scatter edges into CSR-by-dst (stores src index) ----
__global__ void scatter_kernel(const int* __restrict__ src, const int* __restrict__ dst,
                               int* __restrict__ fill, int* __restrict__ csr, int E) {
    int i = blockIdx.x * blockDim.x + threadIdx.x;
    if (i >= E) return;
    int pos = atomicAdd(&fill[dst[i]], 1);
    csr[pos] = src[i];
}

// ---- Y[N,16] = X[N,32] @ W[16,32]^T ----
__global__ void xform32_16(const float* __restrict__ X, const float* __restrict__ W,
                           float* __restrict__ Y, int N) {
    __shared__ float sW[16 * 32];
    for (int t = threadIdx.x; t < 512; t += blockDim.x) sW[t] = W[t];
    __syncthreads();
    int i = blockIdx.x * blockDim.x + threadIdx.x;
    if (i >= N) return;
    float xv[32];
    const float4* xp = (const float4*)(X + (size_t)i * 32);
#pragma unroll
    for (int q = 0; q < 8; q++) {
        float4 v = xp[q];
        xv[4*q+0] = v.x; xv[4*q+1] = v.y; xv[4*q+2] = v.z; xv[4*q+3] = v.w;
    }
    float4* yp = (float4*)(Y + (size_t)i * 16);
#pragma unroll
    for (int j4 = 0; j4 < 4; j4++) {
        float acc[4];
#pragma unroll
        for (int jj = 0; jj < 4; jj++) {
            int j = j4 * 4 + jj;
            float a = 0.f;
#pragma unroll
            for (int k = 0; k < 32; k++) a += xv[k] * sW[j * 32 + k];
            acc[jj] = a;
        }
        float4 o; o.x = acc[0]; o.y = acc[1]; o.z = acc[2]; o.w = acc[3];
        yp[j4] = o;
    }
}

// ---- Y[N,16] = X[N,16] @ W[16,16]^T ----
__global__ void xform16_16(const float* __restrict__ X, const float* __restrict__ W,
                           float* __restrict__ Y, int N) {
    __shared__ float sW[16 * 16];
    for (int t = threadIdx.x; t < 256; t += blockDim.x) sW[t] = W[t];
    __syncthreads();
    int i = blockIdx.x * blockDim.x + threadIdx.x;
    if (i >= N) return;
    float xv[16];
    const float4* xp = (const float4*)(X + (size_t)i * 16);
#pragma unroll
    for (int q = 0; q < 4; q++) {
        float4 v = xp[q];
        xv[4*q+0] = v.x; xv[4*q+1] = v.y; xv[4*q+2] = v.z; xv[4*q+3] = v.w;
    }
    float4* yp = (float4*)(Y + (size_t)i * 16);
#pragma unroll
    for (int j4 = 0; j4 < 4; j4++) {
        float acc[4];
#pragma unroll
        for (int jj = 0; jj < 4; jj++) {
            int j = j4 * 4 + jj;
            float a = 0.f;
#pragma unroll
            for (int k = 0; k < 16; k++) a += xv[k] * sW[j * 16 + k];
            acc[jj] = a;
        }
        float4 o; o.x = acc[0]; o.y = acc[1]; o.z = acc[2]; o.w = acc[3];
        yp[j4] = o;
    }
}

// ---- gather aggregation from CSR: 4 lanes per node, float4 per lane ----
// out[d,:] = sum_e H[src(e),:]*dinv[s]*dinv[d]  +  H[d,:]*dinv[d]^2  (+b, relu)
template <bool RELU>
__global__ void agg_csr(const int* __restrict__ rowptr, const int* __restrict__ csr,
                        const float* __restrict__ dinv, const float* __restrict__ H,
                        const float* __restrict__ bias, float* __restrict__ out, int N) {
    int t = threadIdx.x;
    int node = blockIdx.x * 64 + (t >> 2);
    int q = t & 3;
    if (node >= N) return;
    float dd = dinv[node];
    const float4* H4 = (const float4*)H;
    float4 self = H4[(size_t)node * 4 + q];
    float s2 = dd * dd;
    float4 acc;
    acc.x = self.x * s2; acc.y = self.y * s2; acc.z = self.z * s2; acc.w = self.w * s2;
    int beg = rowptr[node], end = rowptr[node + 1];
    for (int e = beg; e < end; e++) {
        int s = csr[e];
        float nrm = dinv[s] * dd;
        float4 h = H4[(size_t)s * 4 + q];
        acc.x += h.x * nrm; acc.y += h.y * nrm; acc.z += h.z * nrm; acc.w += h.w * nrm;
    }
    if (RELU) {
        float4 b = ((const float4*)bias)[q];
        acc.x = fmaxf(acc.x + b.x, 0.f);
        acc.y = fmaxf(acc.y + b.y, 0.f);
        acc.z = fmaxf(acc.z + b.z, 0.f);
        acc.w = fmaxf(acc.w + b.w, 0.f);
    }
    ((float4*)out)[(size_t)node * 4 + q] = acc;
}

// ---- segmented mean-pool using sorted batch: 16 lanes per node-strip ----
__global__ void pool_kernel(const float* __restrict__ B, const int* __restrict__ batch,
                            float* __restrict__ pooled, float* __restrict__ cnt, int N) {
    int t = blockIdx.x * blockDim.x + threadIdx.x;
    int strip = t >> 4, c = t & 15;
    int i0 = strip * POOL_L;
    if (i0 >= N) return;
    int iend = i0 + POOL_L; if (iend > N) iend = N;
    int g = batch[i0];
    float acc = 0.f, cacc = 0.f;
    for (int i = i0; i < iend; i++) {
        int gi = batch[i];
        if (gi != g) {
            atomicAdd(&pooled[(size_t)g * 16 + c], acc);
            if (c == 0) atomicAdd(&cnt[g], cacc);
            acc = 0.f; cacc = 0.f; g = gi;
        }
        acc += B[(size_t)i * 16 + c];
        cacc += 1.0f;
    }
    atomicAdd(&pooled[(size_t)g * 16 + c], acc);
    if (c == 0) atomicAdd(&cnt[g], cacc);
}

// ---- head: mean finish (+b2), logits = pooled @ Wl^T + bl, softmax ----
__global__ void head_kernel(const float* __restrict__ pooled, const float* __restrict__ cnt,
                            const float* __restrict__ b2, const float* __restrict__ Wl,
                            const float* __restrict__ bl, float* __restrict__ out) {
    int g = blockIdx.x * blockDim.x + threadIdx.x;
    if (g >= NG) return;
    float c = cnt[g];
    c = c > 1.0f ? c : 1.0f;
    float inv = 1.0f / c;
    float p[16];
#pragma unroll
    for (int j = 0; j < 16; j++) p[j] = pooled[(size_t)g * 16 + j] * inv + b2[j];
    float logits[5], m = -INFINITY;
#pragma unroll
    for (int r = 0; r < 5; r++) {
        float a = bl[r];
#pragma unroll
        for (int j = 0; j < 16; j++) a += p[j] * Wl[r * 16 + j];
        logits[r] = a;
        m = fmaxf(m, a);
    }
    float s = 0.f;
#pragma unroll
    for (int r = 0; r < 5; r++) { logits[r] = expf(logits[r] - m); s += logits[r]; }
    float is = 1.0f / s;
#pragma unroll
    for (int r = 0; r < 5; r++) out[(size_t)g * 5 + r] = logits[r] * is;
}

static inline size_t rnd4(size_t x) { return (x + 3) & ~(size_t)3; }

extern "C" void kernel_launch(void* const* d_in, const int* in_sizes, int n_in,
                              void* d_out, int out_size, void* d_ws, size_t ws_size,
                              hipStream_t stream) {
    const float* x     = (const float*)d_in[0];
    const int*   edge  = (const int*)d_in[1];   // [2, E]: first E = src, next E = dst
    const int*   batch = (const int*)d_in[2];
    const float* W1    = (const float*)d_in[3];
    const float* b1    = (const float*)d_in[4];
    const float* W2    = (const float*)d_in[5];
    const float* b2    = (const float*)d_in[6];
    const float* Wl    = (const float*)d_in[7];
    const float* bl    = (const float*)d_in[8];

    const int N = in_sizes[0] / 32;
    const int E = in_sizes[1] / 2;
    const int* src = edge;
    const int* dst = edge + E;

    // workspace layout (element offsets rounded to 16B)
    char* ws = (char*)d_ws;
    size_t off = 0;
    int*   degfill = (int*)(ws + off);   off += rnd4((size_t)N) * 4;
    float* pooled  = (float*)(ws + off); off += rnd4((size_t)NG * 16) * 4;
    float* cnt     = (float*)(ws + off); off += rnd4((size_t)NG) * 4;
    size_t zbytes  = off;                // [degfill | pooled | cnt] zeroed together
    float* dinv    = (float*)(ws + off); off += rnd4((size_t)N) * 4;
    int*   rowptr  = (int*)(ws + off);   off += rnd4((size_t)N + 1) * 4;
    int*   csr     = (int*)(ws + off);   off += rnd4((size_t)E) * 4;
    float* A       = (float*)(ws + off); off += rnd4((size_t)N * 16) * 4;
    float* B       = (float*)(ws + off); off += rnd4((size_t)N * 16) * 4;

    hipMemsetAsync(d_ws, 0, zbytes, stream);

    const int BS = 256;
    int gE = (E + BS - 1) / BS;
    int gN = (N + BS - 1) / BS;

    // CSR build
    deg_kernel<<<gE, BS, 0, stream>>>(dst, degfill, E);
    scan_kernel<<<1, SCAN_T, 0, stream>>>(degfill, dinv, rowptr, N);
    scatter_kernel<<<gE, BS, 0, stream>>>(src, dst, degfill, csr, E);

    // conv1: A = x@W1^T ; B = relu(gather(A) + self + b1)
    xform32_16<<<gN, BS, 0, stream>>>(x, W1, A, N);
    int gAgg = (N + 63) / 64;
    agg_csr<true><<<gAgg, BS, 0, stream>>>(rowptr, csr, dinv, A, b1, B, N);

    // conv2: A = B@W2^T ; B = gather(A) + self   (b2 deferred to head)
    xform16_16<<<gN, BS, 0, stream>>>(B, W2, A, N);
    agg_csr<false><<<gAgg, BS, 0, stream>>>(rowptr, csr, dinv, A, nullptr, B, N);

    // segmented mean pool + head
    int strips = (N + POOL_L - 1) / POOL_L;
    int gPool = (strips * 16 + BS - 1) / BS;
    pool_kernel<<<gPool, BS, 0, stream>>>(B, batch, pooled, cnt, N);
    head_kernel<<<(NG + BS - 1) / BS, BS, 0, stream>>>(pooled, cnt, b2, Wl, bl, (float*)d_out);
}

// Round 3
// 345.829 us; speedup vs baseline: 1.9729x; 1.9729x over previous
//
#include <hip/hip_runtime.h>
#include <math.h>

#define NG 1000
#define POOL_L 128
#define SBLK 256
#define SITEMS 8
#define SCHUNK (SBLK * SITEMS)   // 2048 items per scan block

// ---- integer in-degree over dst ----
__global__ void deg_kernel(const int* __restrict__ dst, int* __restrict__ degi, int E) {
    int i = blockIdx.x * blockDim.x + threadIdx.x;
    if (i < E) atomicAdd(&degi[dst[i]], 1);
}

// ---- scan phase 1: per-block sums of degi; also compute dinv ----
__global__ void __launch_bounds__(SBLK) scan_part(const int* __restrict__ degi,
                                                  float* __restrict__ dinv,
                                                  int* __restrict__ bsum, int N) {
    int b = blockIdx.x, t = threadIdx.x;
    int base = b * SCHUNK + t * SITEMS;
    int s = 0;
#pragma unroll
    for (int k = 0; k < SITEMS; k++) {
        int i = base + k;
        if (i < N) {
            int d = degi[i];
            s += d;
            dinv[i] = rsqrtf((float)d + 1.0f);   // self-loop adds +1
        }
    }
    __shared__ int sm[SBLK];
    sm[t] = s;
    __syncthreads();
    for (int o = SBLK / 2; o > 0; o >>= 1) {
        if (t < o) sm[t] += sm[t + o];
        __syncthreads();
    }
    if (t == 0) bsum[b] = sm[0];
}

// ---- scan phase 2: exclusive scan of block sums (nb <= 256) ----
__global__ void __launch_bounds__(256) scan_bsum(int* __restrict__ bsum, int nb) {
    __shared__ int sm[256];
    int t = threadIdx.x;
    int v = (t < nb) ? bsum[t] : 0;
    sm[t] = v;
    __syncthreads();
    for (int o = 1; o < 256; o <<= 1) {
        int u = 0;
        if (t >= o) u = sm[t - o];
        __syncthreads();
        sm[t] += u;
        __syncthreads();
    }
    if (t < nb) bsum[t] = sm[t] - v;   // exclusive
}

// ---- scan phase 3: intra-block exclusive scan -> rowptr & fill ----
__global__ void __launch_bounds__(SBLK) scan_final(const int* __restrict__ degi,
                                                   const int* __restrict__ bsum,
                                                   int* __restrict__ rowptr,
                                                   int* __restrict__ fill, int N) {
    int b = blockIdx.x, t = threadIdx.x;
    int base = b * SCHUNK + t * SITEMS;
    int loc[SITEMS];
    int s = 0;
#pragma unroll
    for (int k = 0; k < SITEMS; k++) {
        int i = base + k;
        int d = (i < N) ? degi[i] : 0;
        loc[k] = d;
        s += d;
    }
    __shared__ int sm[SBLK];
    sm[t] = s;
    __syncthreads();
    for (int o = 1; o < SBLK; o <<= 1) {
        int u = 0;
        if (t >= o) u = sm[t - o];
        __syncthreads();
        sm[t] += u;
        __syncthreads();
    }
    int run = bsum[b] + sm[t] - s;   // global exclusive prefix for this thread's chunk
#pragma unroll
    for (int k = 0; k < SITEMS; k++) {
        int i = base + k;
        if (i < N) {
            rowptr[i] = run;
            fill[i]   = run;
            run += loc[k];
            if (i == N - 1) rowptr[N] = run;
        }
    }
}

// ---- scatter edges into CSR-by-dst (stores src index) ----
__global__ void scatter_kernel(const int* __restrict__ src, const int* __restrict__ dst,
                               int* __restrict__ fill, int* __restrict__ csr, int E) {
    int i = blockIdx.x * blockDim.x + threadIdx.x;
    if (i >= E) return;
    int pos = atomicAdd(&fill[dst[i]], 1);
    csr[pos] = src[i];
}

// ---- Y[N,16] = X[N,32] @ W[16,32]^T ----
__global__ void xform32_16(const float* __restrict__ X, const float* __restrict__ W,
                           float* __restrict__ Y, int N) {
    __shared__ float sW[16 * 32];
    for (int t = threadIdx.x; t < 512; t += blockDim.x) sW[t] = W[t];
    __syncthreads();
    int i = blockIdx.x * blockDim.x + threadIdx.x;
    if (i >= N) return;
    float xv[32];
    const float4* xp = (const float4*)(X + (size_t)i * 32);
#pragma unroll
    for (int q = 0; q < 8; q++) {
        float4 v = xp[q];
        xv[4*q+0] = v.x; xv[4*q+1] = v.y; xv[4*q+2] = v.z; xv[4*q+3] = v.w;
    }
    float4* yp = (float4*)(Y + (size_t)i * 16);
#pragma unroll
    for (int j4 = 0; j4 < 4; j4++) {
        float acc[4];
#pragma unroll
        for (int jj = 0; jj < 4; jj++) {
            int j = j4 * 4 + jj;
            float a = 0.f;
#pragma unroll
            for (int k = 0; k < 32; k++) a += xv[k] * sW[j * 32 + k];
            acc[jj] = a;
        }
        float4 o; o.x = acc[0]; o.y = acc[1]; o.z = acc[2]; o.w = acc[3];
        yp[j4] = o;
    }
}

// ---- Y[N,16] = X[N,16] @ W[16,16]^T ----
__global__ void xform16_16(const float* __restrict__ X, const float* __restrict__ W,
                           float* __restrict__ Y, int N) {
    __shared__ float sW[16 * 16];
    for (int t = threadIdx.x; t < 256; t += blockDim.x) sW[t] = W[t];
    __syncthreads();
    int i = blockIdx.x * blockDim.x + threadIdx.x;
    if (i >= N) return;
    float xv[16];
    const float4* xp = (const float4*)(X + (size_t)i * 16);
#pragma unroll
    for (int q = 0; q < 4; q++) {
        float4 v = xp[q];
        xv[4*q+0] = v.x; xv[4*q+1] = v.y; xv[4*q+2] = v.z; xv[4*q+3] = v.w;
    }
    float4* yp = (float4*)(Y + (size_t)i * 16);
#pragma unroll
    for (int j4 = 0; j4 < 4; j4++) {
        float acc[4];
#pragma unroll
        for (int jj = 0; jj < 4; jj++) {
            int j = j4 * 4 + jj;
            float a = 0.f;
#pragma unroll
            for (int k = 0; k < 16; k++) a += xv[k] * sW[j * 16 + k];
            acc[jj] = a;
        }
        float4 o; o.x = acc[0]; o.y = acc[1]; o.z = acc[2]; o.w = acc[3];
        yp[j4] = o;
    }
}

// ---- gather aggregation from CSR: 4 lanes per node, float4 per lane ----
template <bool RELU>
__global__ void agg_csr(const int* __restrict__ rowptr, const int* __restrict__ csr,
                        const float* __restrict__ dinv, const float* __restrict__ H,
                        const float* __restrict__ bias, float* __restrict__ out, int N) {
    int t = threadIdx.x;
    int node = blockIdx.x * 64 + (t >> 2);
    int q = t & 3;
    if (node >= N) return;
    float dd = dinv[node];
    const float4* H4 = (const float4*)H;
    float4 self = H4[(size_t)node * 4 + q];
    float s2 = dd * dd;
    float4 acc;
    acc.x = self.x * s2; acc.y = self.y * s2; acc.z = self.z * s2; acc.w = self.w * s2;
    int beg = rowptr[node], end = rowptr[node + 1];
    for (int e = beg; e < end; e++) {
        int s = csr[e];
        float nrm = dinv[s] * dd;
        float4 h = H4[(size_t)s * 4 + q];
        acc.x += h.x * nrm; acc.y += h.y * nrm; acc.z += h.z * nrm; acc.w += h.w * nrm;
    }
    if (RELU) {
        float4 b = ((const float4*)bias)[q];
        acc.x = fmaxf(acc.x + b.x, 0.f);
        acc.y = fmaxf(acc.y + b.y, 0.f);
        acc.z = fmaxf(acc.z + b.z, 0.f);
        acc.w = fmaxf(acc.w + b.w, 0.f);
    }
    ((float4*)out)[(size_t)node * 4 + q] = acc;
}

// ---- segmented mean-pool using sorted batch: 16 lanes per node-strip ----
__global__ void pool_kernel(const float* __restrict__ B, const int* __restrict__ batch,
                            float* __restrict__ pooled, float* __restrict__ cnt, int N) {
    int t = blockIdx.x * blockDim.x + threadIdx.x;
    int strip = t >> 4, c = t & 15;
    int i0 = strip * POOL_L;
    if (i0 >= N) return;
    int iend = i0 + POOL_L; if (iend > N) iend = N;
    int g = batch[i0];
    float acc = 0.f, cacc = 0.f;
    for (int i = i0; i < iend; i++) {
        int gi = batch[i];
        if (gi != g) {
            atomicAdd(&pooled[(size_t)g * 16 + c], acc);
            if (c == 0) atomicAdd(&cnt[g], cacc);
            acc = 0.f; cacc = 0.f; g = gi;
        }
        acc += B[(size_t)i * 16 + c];
        cacc += 1.0f;
    }
    atomicAdd(&pooled[(size_t)g * 16 + c], acc);
    if (c == 0) atomicAdd(&cnt[g], cacc);
}

// ---- head: mean finish (+b2), logits = pooled @ Wl^T + bl, softmax ----
__global__ void head_kernel(const float* __restrict__ pooled, const float* __restrict__ cnt,
                            const float* __restrict__ b2, const float* __restrict__ Wl,
                            const float* __restrict__ bl, float* __restrict__ out) {
    int g = blockIdx.x * blockDim.x + threadIdx.x;
    if (g >= NG) return;
    float c = cnt[g];
    c = c > 1.0f ? c : 1.0f;
    float inv = 1.0f / c;
    float p[16];
#pragma unroll
    for (int j = 0; j < 16; j++) p[j] = pooled[(size_t)g * 16 + j] * inv + b2[j];
    float logits[5], m = -INFINITY;
#pragma unroll
    for (int r = 0; r < 5; r++) {
        float a = bl[r];
#pragma unroll
        for (int j = 0; j < 16; j++) a += p[j] * Wl[r * 16 + j];
        logits[r] = a;
        m = fmaxf(m, a);
    }
    float s = 0.f;
#pragma unroll
    for (int r = 0; r < 5; r++) { logits[r] = expf(logits[r] - m); s += logits[r]; }
    float is = 1.0f / s;
#pragma unroll
    for (int r = 0; r < 5; r++) out[(size_t)g * 5 + r] = logits[r] * is;
}

static inline size_t rnd4(size_t x) { return (x + 3) & ~(size_t)3; }

extern "C" void kernel_launch(void* const* d_in, const int* in_sizes, int n_in,
                              void* d_out, int out_size, void* d_ws, size_t ws_size,
                              hipStream_t stream) {
    const float* x     = (const float*)d_in[0];
    const int*   edge  = (const int*)d_in[1];   // [2, E]: first E = src, next E = dst
    const int*   batch = (const int*)d_in[2];
    const float* W1    = (const float*)d_in[3];
    const float* b1    = (const float*)d_in[4];
    const float* W2    = (const float*)d_in[5];
    const float* b2    = (const float*)d_in[6];
    const float* Wl    = (const float*)d_in[7];
    const float* bl    = (const float*)d_in[8];

    const int N = in_sizes[0] / 32;
    const int E = in_sizes[1] / 2;
    const int* src = edge;
    const int* dst = edge + E;

    // workspace layout
    char* ws = (char*)d_ws;
    size_t off = 0;
    int*   degi   = (int*)(ws + off);   off += rnd4((size_t)N) * 4;
    float* pooled = (float*)(ws + off); off += rnd4((size_t)NG * 16) * 4;
    float* cnt    = (float*)(ws + off); off += rnd4((size_t)NG) * 4;
    size_t zbytes = off;                // [degi | pooled | cnt] zeroed together
    float* dinv   = (float*)(ws + off); off += rnd4((size_t)N) * 4;
    int*   rowptr = (int*)(ws + off);   off += rnd4((size_t)N + 1) * 4;
    int*   fill   = (int*)(ws + off);   off += rnd4((size_t)N) * 4;
    int*   bsum   = (int*)(ws + off);   off += 256 * 4;
    int*   csr    = (int*)(ws + off);   off += rnd4((size_t)E) * 4;
    float* A      = (float*)(ws + off); off += rnd4((size_t)N * 16) * 4;
    float* B      = (float*)(ws + off); off += rnd4((size_t)N * 16) * 4;

    hipMemsetAsync(d_ws, 0, zbytes, stream);

    const int BS = 256;
    int gE = (E + BS - 1) / BS;
    int gN = (N + BS - 1) / BS;
    int nsb = (N + SCHUNK - 1) / SCHUNK;

    // CSR build: deg -> multi-block scan -> scatter
    deg_kernel<<<gE, BS, 0, stream>>>(dst, degi, E);
    scan_part<<<nsb, SBLK, 0, stream>>>(degi, dinv, bsum, N);
    scan_bsum<<<1, 256, 0, stream>>>(bsum, nsb);
    scan_final<<<nsb, SBLK, 0, stream>>>(degi, bsum, rowptr, fill, N);
    scatter_kernel<<<gE, BS, 0, stream>>>(src, dst, fill, csr, E);

    // conv1: A = x@W1^T ; B = relu(gather(A) + self + b1)
    xform32_16<<<gN, BS, 0, stream>>>(x, W1, A, N);
    int gAgg = (N + 63) / 64;
    agg_csr<true><<<gAgg, BS, 0, stream>>>(rowptr, csr, dinv, A, b1, B, N);

    // conv2: A = B@W2^T ; B = gather(A) + self   (b2 deferred to head)
    xform16_16<<<gN, BS, 0, stream>>>(B, W2, A, N);
    agg_csr<false><<<gAgg, BS, 0, stream>>>(rowptr, csr, dinv, A, nullptr, B, N);

    // segmented mean pool + head
    int strips = (N + POOL_L - 1) / POOL_L;
    int gPool = (strips * 16 + BS - 1) / BS;
    pool_kernel<<<gPool, BS, 0, stream>>>(B, batch, pooled, cnt, N);
    head_kernel<<<(NG + BS - 1) / BS, BS, 0, stream>>>(pooled, cnt, b2, Wl, bl, (float*)d_out);
}